// Round 9
// baseline (155.367 us; speedup 1.0000x reference)
//
#include <hip/hip_runtime.h>
#include <hip/hip_bf16.h>

#define NTOT   8192
#define BHALF  4096
#define DDIM   256
#define NRG    4      // row-groups (2048 rows each); s_part has NRG partial copies
#define EXPSCALE 14.4269504088896341f   // 10 / ln(2): exp(10x) = exp2(EXPSCALE*x)

typedef __attribute__((ext_vector_type(8))) short bf16x8_t;  // 8 bf16 = 4 VGPRs
typedef __attribute__((ext_vector_type(4))) float f32x4_t;   // MFMA C/D

__device__ inline unsigned short f2bf(float x) {
    __hip_bfloat16 h = __float2bfloat16(x);
    return __builtin_bit_cast(unsigned short, h);
}

// ---- kernel 1: normalize pair k (rows k, k+B) -> bf16 zn; posdot ----
__global__ void norm_pair_kernel(const float* __restrict__ zi,
                                 const float* __restrict__ zj,
                                 unsigned short* __restrict__ zn,
                                 float* __restrict__ posdot) {
    int gtid = blockIdx.x * 256 + threadIdx.x;
    int k    = gtid >> 6;
    int lane = gtid & 63;
    float4 vi = reinterpret_cast<const float4*>(zi + (size_t)k * DDIM)[lane];
    float4 vj = reinterpret_cast<const float4*>(zj + (size_t)k * DDIM)[lane];
    float ssi = vi.x*vi.x + vi.y*vi.y + vi.z*vi.z + vi.w*vi.w;
    float ssj = vj.x*vj.x + vj.y*vj.y + vj.z*vj.z + vj.w*vj.w;
    float dot = vi.x*vj.x + vi.y*vj.y + vi.z*vj.z + vi.w*vj.w;
    #pragma unroll
    for (int off = 32; off >= 1; off >>= 1) {
        ssi += __shfl_xor(ssi, off);
        ssj += __shfl_xor(ssj, off);
        dot += __shfl_xor(dot, off);
    }
    float ri = 1.0f / fmaxf(sqrtf(ssi), 1e-8f);
    float rj = 1.0f / fmaxf(sqrtf(ssj), 1e-8f);
    ushort4 oi, oj;
    oi.x = f2bf(vi.x * ri); oi.y = f2bf(vi.y * ri);
    oi.z = f2bf(vi.z * ri); oi.w = f2bf(vi.w * ri);
    oj.x = f2bf(vj.x * rj); oj.y = f2bf(vj.y * rj);
    oj.z = f2bf(vj.z * rj); oj.w = f2bf(vj.w * rj);
    reinterpret_cast<ushort4*>(zn + (size_t)k * DDIM)[lane] = oi;
    reinterpret_cast<ushort4*>(zn + (size_t)(k + BHALF) * DDIM)[lane] = oj;
    if (lane == 0) posdot[k] = dot * ri * rj * 10.0f;
}

// ---- kernel 2: persistent col-strip GEMM + exp col-sum (= row-sum by symmetry).
// Block (cs, rg): 64 cols (staged to LDS ONCE), 2048 rows in 8x256 slabs.
// NO barriers in the row loop: A-frags stream global->VGPR (zn is L2-resident),
// compiler free to pipeline. rf=4 -> each LDS B-read feeds 4 MFMAs.
// Col accumulators in registers across the loop -> no atomics; plain store of
// 64 floats into the block's private s_part[rg] slice.
// __launch_bounds__(256,1): lift VGPR cap to 512 so afrag[4][8] (128 VGPR)
// stays resident (min-waves>=2 made the allocator clamp to 64 and spill: r5/r7).
__global__ void __launch_bounds__(256, 1)
gemm_colsum_kernel(const unsigned short* __restrict__ zn,
                   float* __restrict__ s_part) {
    __shared__ unsigned short ldsB[64 * 256];   // 32 KB, 16B chunks xor-swizzled
    __shared__ float colLDS[4][64];

    const int tid  = threadIdx.x;
    const int lane = tid & 63;
    const int wv   = tid >> 6;        // 0..3 -> 64-row slice of each 256-row slab
    const int m    = lane & 15;
    const int quad = lane >> 4;
    const int cs   = blockIdx.x;      // 0..127 col strip (64 cols)
    const int rg   = blockIdx.y;      // 0..3 row group (2048 rows)
    const int C0   = cs << 6;

    // stage B strip once: 64 cols x 256 k; chunk c of row r -> slot (c ^ (r&7))
    #pragma unroll
    for (int t = 0; t < 8; ++t) {
        int ci = t * 256 + tid;
        int r = ci >> 5, c = ci & 31;
        bf16x8_t v = *reinterpret_cast<const bf16x8_t*>(
                         zn + (size_t)(C0 + r) * DDIM + c * 8);
        *reinterpret_cast<bf16x8_t*>(&ldsB[r * 256 + ((c ^ (r & 7)) << 3)]) = v;
    }
    __syncthreads();

    float expacc[4] = {0.f, 0.f, 0.f, 0.f};
    const int diagSlab = C0 >> 8;     // 256-row slab index containing cols C0..C0+63

    for (int rb = 0; rb < 8; ++rb) {
        const int rowbase = (rg << 11) + (rb << 8);
        const bool isDiag = ((rowbase >> 8) == diagSlab);

        // A fragments: rows rowbase + wv*64 + rf*16 + m, k = kk*32 + quad*8 (+j)
        bf16x8_t afrag[4][8];
        #pragma unroll
        for (int rf = 0; rf < 4; ++rf) {
            const unsigned short* arow =
                zn + (size_t)(rowbase + wv*64 + rf*16 + m) * DDIM;
            #pragma unroll
            for (int kk = 0; kk < 8; ++kk)
                afrag[rf][kk] = *reinterpret_cast<const bf16x8_t*>(arow + kk*32 + quad*8);
        }

        #pragma unroll
        for (int cf = 0; cf < 4; ++cf) {
            f32x4_t cacc[4];
            #pragma unroll
            for (int rf = 0; rf < 4; ++rf) cacc[rf] = (f32x4_t){0.f,0.f,0.f,0.f};
            #pragma unroll
            for (int kk = 0; kk < 8; ++kk) {
                bf16x8_t b = *reinterpret_cast<const bf16x8_t*>(
                    &ldsB[(cf*16 + m) * 256 + (((kk*4 + quad) ^ (m & 7)) << 3)]);
                #pragma unroll
                for (int rf = 0; rf < 4; ++rf)
                    cacc[rf] = __builtin_amdgcn_mfma_f32_16x16x32_bf16(
                        afrag[rf][kk], b, cacc[rf], 0, 0, 0);
            }
            // accumulate exp into the column accumulator (sum over this slab's rows)
            const int gc = C0 + cf*16 + m;
            float acc = expacc[cf];
            if (isDiag) {
                #pragma unroll
                for (int rf = 0; rf < 4; ++rf)
                    #pragma unroll
                    for (int r = 0; r < 4; ++r) {
                        int gr = rowbase + wv*64 + rf*16 + quad*4 + r;
                        float e = exp2f(cacc[rf][r] * EXPSCALE);
                        acc += (gr == gc) ? 0.f : e;
                    }
            } else {
                #pragma unroll
                for (int rf = 0; rf < 4; ++rf)
                    #pragma unroll
                    for (int r = 0; r < 4; ++r)
                        acc += exp2f(cacc[rf][r] * EXPSCALE);
            }
            expacc[cf] = acc;
        }
    }

    // reduce col partial over the 4 quads (rows), combine 4 waves, store (no atomics)
    #pragma unroll
    for (int cf = 0; cf < 4; ++cf) {
        float v = expacc[cf];
        v += __shfl_xor(v, 16);
        v += __shfl_xor(v, 32);
        if (quad == 0) colLDS[wv][cf*16 + m] = v;
    }
    __syncthreads();
    if (tid < 64)
        s_part[(size_t)rg * NTOT + C0 + tid] =
            colLDS[0][tid] + colLDS[1][tid] + colLDS[2][tid] + colLDS[3][tid];
}

// ---- kernel 3: loss_k = log(sum_rg s_part[rg][k]) - posdot[k%B]; masked mean ----
__global__ void finalize_kernel(const float* __restrict__ s_part,
                                const float* __restrict__ posdot,
                                const unsigned char* __restrict__ mask,
                                float* __restrict__ out) {
    int tid = threadIdx.x, lane = tid & 63, wv = tid >> 6;
    float tot = 0.f, cnt = 0.f;
    #pragma unroll
    for (int si = 0; si < NTOT / 1024; ++si) {
        int k = si * 1024 + tid;
        int kb = k & (BHALF - 1);
        if (mask[kb] != 0) {
            float sk = s_part[k] + s_part[NTOT + k]
                     + s_part[2*NTOT + k] + s_part[3*NTOT + k];
            tot += __logf(sk) - posdot[kb];
            cnt += 1.f;
        }
    }
    #pragma unroll
    for (int off = 32; off >= 1; off >>= 1) {
        tot += __shfl_xor(tot, off);
        cnt += __shfl_xor(cnt, off);
    }
    __shared__ float st[16], sc[16];
    if (lane == 0) { st[wv] = tot; sc[wv] = cnt; }
    __syncthreads();
    if (tid == 0) {
        float T = 0.f, C = 0.f;
        #pragma unroll
        for (int i = 0; i < 16; ++i) { T += st[i]; C += sc[i]; }
        out[0] = (C > 0.f) ? (T / fmaxf(C, 1.f)) : 0.f;
    }
}

extern "C" void kernel_launch(void* const* d_in, const int* in_sizes, int n_in,
                              void* d_out, int out_size, void* d_ws, size_t ws_size,
                              hipStream_t stream) {
    const float* zi = (const float*)d_in[0];
    const float* zj = (const float*)d_in[1];
    const unsigned char* mask = (const unsigned char*)d_in[2];
    float* out = (float*)d_out;

    // ws: [0,4MB) zn bf16; s_part[NRG][8192] f32; posdot[4096] f32
    unsigned short* zn = (unsigned short*)d_ws;
    float* s_part = (float*)((char*)d_ws + (size_t)NTOT * DDIM * 2);
    float* posdot = s_part + NRG * NTOT;

    norm_pair_kernel<<<dim3(1024), dim3(256), 0, stream>>>(zi, zj, zn, posdot);
    gemm_colsum_kernel<<<dim3(128, NRG), dim3(256), 0, stream>>>(zn, s_part);
    finalize_kernel<<<dim3(1), dim3(1024), 0, stream>>>(s_part, posdot, mask, out);
}

// Round 10
// 119.267 us; speedup vs baseline: 1.3027x; 1.3027x over previous
//
#include <hip/hip_runtime.h>
#include <hip/hip_bf16.h>

#define NTOT   8192
#define BHALF  4096
#define DDIM   256
#define NPART  4
#define EXPSCALE 14.4269504088896341f   // 10 / ln(2): exp(10x) = exp2(EXPSCALE*x)

typedef __attribute__((ext_vector_type(8))) short bf16x8_t;  // 8 bf16 = 4 VGPRs
typedef __attribute__((ext_vector_type(4))) float f32x4_t;   // MFMA C/D

__device__ inline unsigned short f2bf(float x) {
    __hip_bfloat16 h = __float2bfloat16(x);
    return __builtin_bit_cast(unsigned short, h);
}

// ---- kernel 1: normalize pair k (rows k, k+B) -> bf16 zn; posdot; zero s_part ----
__global__ void norm_pair_kernel(const float* __restrict__ zi,
                                 const float* __restrict__ zj,
                                 unsigned short* __restrict__ zn,
                                 float* __restrict__ posdot,
                                 float* __restrict__ s_part) {
    int gtid = blockIdx.x * 256 + threadIdx.x;
    if (gtid < NTOT * NPART) s_part[gtid] = 0.0f;   // done before gemm (stream order)
    int k    = gtid >> 6;
    int lane = gtid & 63;
    float4 vi = reinterpret_cast<const float4*>(zi + (size_t)k * DDIM)[lane];
    float4 vj = reinterpret_cast<const float4*>(zj + (size_t)k * DDIM)[lane];
    float ssi = vi.x*vi.x + vi.y*vi.y + vi.z*vi.z + vi.w*vi.w;
    float ssj = vj.x*vj.x + vj.y*vj.y + vj.z*vj.z + vj.w*vj.w;
    float dot = vi.x*vj.x + vi.y*vj.y + vi.z*vj.z + vi.w*vj.w;
    #pragma unroll
    for (int off = 32; off >= 1; off >>= 1) {
        ssi += __shfl_xor(ssi, off);
        ssj += __shfl_xor(ssj, off);
        dot += __shfl_xor(dot, off);
    }
    float ri = 1.0f / fmaxf(sqrtf(ssi), 1e-8f);
    float rj = 1.0f / fmaxf(sqrtf(ssj), 1e-8f);
    ushort4 oi, oj;
    oi.x = f2bf(vi.x * ri); oi.y = f2bf(vi.y * ri);
    oi.z = f2bf(vi.z * ri); oi.w = f2bf(vi.w * ri);
    oj.x = f2bf(vj.x * rj); oj.y = f2bf(vj.y * rj);
    oj.z = f2bf(vj.z * rj); oj.w = f2bf(vj.w * rj);
    reinterpret_cast<ushort4*>(zn + (size_t)k * DDIM)[lane] = oi;
    reinterpret_cast<ushort4*>(zn + (size_t)(k + BHALF) * DDIM)[lane] = oj;
    if (lane == 0) posdot[k] = dot * ri * rj * 10.0f;
}

// ---- kernel 2: full-matrix fused GEMM + row exp-sum (r2 structure, refined).
// Grid (64,16): block = 128 rows x 512 cols (8 strips of 64 cols).
// A frags resident in registers (rf=2); B strips staged cooperatively to
// xor-swizzled LDS (r9-proven ~0.5 conflicts/read); next strip prefetched
// into registers before the compute phase so global latency overlaps MFMA.
// LDS = 32 KB -> up to 5 blocks/CU; grid gives 4 resident (vs r2's 2).
// No min-waves launch bound (min-waves>=2 clamps VGPR to 64 and spills: r5/r7).
__global__ void __launch_bounds__(256)
gemm_kernel(const unsigned short* __restrict__ zn,
            float* __restrict__ s_part) {
    __shared__ unsigned short ldsB[64 * 256];   // 32 KB

    const int tid  = threadIdx.x;
    const int lane = tid & 63;
    const int wv   = tid >> 6;        // 0..3 -> 32-row slice
    const int m    = lane & 15;
    const int quad = lane >> 4;
    const int bi   = blockIdx.x;      // 0..63 row block (128 rows)
    const int s    = blockIdx.y;      // 0..15 col split (512 cols)
    const int R0   = bi << 7;
    const int CB   = s << 9;

    float* rowPart = s_part + (size_t)(s & (NPART - 1)) * NTOT;

    // A fragments: rows R0 + wv*32 + rf*16 + m, k = kk*32 + quad*8 (+j)
    bf16x8_t afrag[2][8];
    #pragma unroll
    for (int rf = 0; rf < 2; ++rf) {
        const unsigned short* arow = zn + (size_t)(R0 + wv*32 + rf*16 + m) * DDIM;
        #pragma unroll
        for (int kk = 0; kk < 8; ++kk)
            afrag[rf][kk] = *reinterpret_cast<const bf16x8_t*>(arow + kk*32 + quad*8);
    }

    // prefetch strip 0 into registers (8 x 16B chunks per thread)
    bf16x8_t pf[8];
    #pragma unroll
    for (int t = 0; t < 8; ++t) {
        int ci = t * 256 + tid;
        int r = ci >> 5, c = ci & 31;
        pf[t] = *reinterpret_cast<const bf16x8_t*>(zn + (size_t)(CB + r) * DDIM + c * 8);
    }

    float rowacc[2][4] = {{0.f,0.f,0.f,0.f},{0.f,0.f,0.f,0.f}};

    for (int it = 0; it < 8; ++it) {
        const int C0 = CB + it * 64;
        const bool isDiag = ((C0 >> 7) == bi);   // strip's 64 cols inside this row block?

        __syncthreads();   // previous strip's readers done
        // write prefetched strip: chunk c of row r -> slot (c ^ (r&7))
        #pragma unroll
        for (int t = 0; t < 8; ++t) {
            int ci = t * 256 + tid;
            int r = ci >> 5, c = ci & 31;
            *reinterpret_cast<bf16x8_t*>(&ldsB[r * 256 + ((c ^ (r & 7)) << 3)]) = pf[t];
        }
        __syncthreads();   // staging visible

        // prefetch next strip (loads issue now, waitcnt lands before next write)
        if (it < 7) {
            #pragma unroll
            for (int t = 0; t < 8; ++t) {
                int ci = t * 256 + tid;
                int r = ci >> 5, c = ci & 31;
                pf[t] = *reinterpret_cast<const bf16x8_t*>(
                            zn + (size_t)(C0 + 64 + r) * DDIM + c * 8);
            }
        }

        #pragma unroll
        for (int cf = 0; cf < 4; ++cf) {
            f32x4_t c0 = (f32x4_t){0.f,0.f,0.f,0.f};
            f32x4_t c1 = (f32x4_t){0.f,0.f,0.f,0.f};
            #pragma unroll
            for (int kk = 0; kk < 8; ++kk) {
                bf16x8_t b = *reinterpret_cast<const bf16x8_t*>(
                    &ldsB[(cf*16 + m) * 256 + (((kk*4 + quad) ^ (m & 7)) << 3)]);
                c0 = __builtin_amdgcn_mfma_f32_16x16x32_bf16(afrag[0][kk], b, c0, 0, 0, 0);
                c1 = __builtin_amdgcn_mfma_f32_16x16x32_bf16(afrag[1][kk], b, c1, 0, 0, 0);
            }
            const int gc = C0 + cf*16 + m;
            #pragma unroll
            for (int r = 0; r < 4; ++r) {
                int gr0 = R0 + wv*32 + quad*4 + r;
                float e0 = exp2f(c0[r] * EXPSCALE);
                float e1 = exp2f(c1[r] * EXPSCALE);
                if (isDiag && gr0 == gc)        e0 = 0.f;
                if (isDiag && (gr0 + 16) == gc) e1 = 0.f;
                rowacc[0][r] += e0;
                rowacc[1][r] += e1;
            }
        }
    }

    // row totals: reduce over 16 m-lanes sharing a row, one atomic per row
    #pragma unroll
    for (int rf = 0; rf < 2; ++rf)
        #pragma unroll
        for (int r = 0; r < 4; ++r) {
            float v = rowacc[rf][r];
            v += __shfl_xor(v, 1);
            v += __shfl_xor(v, 2);
            v += __shfl_xor(v, 4);
            v += __shfl_xor(v, 8);
            if (m == 0)
                atomicAdd(&rowPart[R0 + wv*32 + rf*16 + quad*4 + r], v);
        }
}

// ---- kernel 3: loss_k = log(sum_p s_part[p][k]) - posdot[k%B]; masked mean ----
__global__ void finalize_kernel(const float* __restrict__ s_part,
                                const float* __restrict__ posdot,
                                const unsigned char* __restrict__ mask,
                                float* __restrict__ out) {
    int tid = threadIdx.x, lane = tid & 63, wv = tid >> 6;
    float tot = 0.f, cnt = 0.f;
    #pragma unroll
    for (int si = 0; si < NTOT / 1024; ++si) {
        int k = si * 1024 + tid;
        int kb = k & (BHALF - 1);
        if (mask[kb] != 0) {
            float sk = s_part[k] + s_part[NTOT + k]
                     + s_part[2*NTOT + k] + s_part[3*NTOT + k];
            tot += __logf(sk) - posdot[kb];
            cnt += 1.f;
        }
    }
    #pragma unroll
    for (int off = 32; off >= 1; off >>= 1) {
        tot += __shfl_xor(tot, off);
        cnt += __shfl_xor(cnt, off);
    }
    __shared__ float st[16], sc[16];
    if (lane == 0) { st[wv] = tot; sc[wv] = cnt; }
    __syncthreads();
    if (tid == 0) {
        float T = 0.f, C = 0.f;
        #pragma unroll
        for (int i = 0; i < 16; ++i) { T += st[i]; C += sc[i]; }
        out[0] = (C > 0.f) ? (T / fmaxf(C, 1.f)) : 0.f;
    }
}

extern "C" void kernel_launch(void* const* d_in, const int* in_sizes, int n_in,
                              void* d_out, int out_size, void* d_ws, size_t ws_size,
                              hipStream_t stream) {
    const float* zi = (const float*)d_in[0];
    const float* zj = (const float*)d_in[1];
    const unsigned char* mask = (const unsigned char*)d_in[2];
    float* out = (float*)d_out;

    // ws: [0,4MB) zn bf16; s_part[NPART][8192] f32; posdot[4096] f32
    unsigned short* zn = (unsigned short*)d_ws;
    float* s_part = (float*)((char*)d_ws + (size_t)NTOT * DDIM * 2);
    float* posdot = s_part + NPART * NTOT;

    norm_pair_kernel<<<dim3(1024), dim3(256), 0, stream>>>(zi, zj, zn, posdot, s_part);
    gemm_kernel<<<dim3(64, 16), dim3(256), 0, stream>>>(zn, s_part);
    finalize_kernel<<<dim3(1), dim3(1024), 0, stream>>>(s_part, posdot, mask, out);
}